// Round 12
// baseline (594.220 us; speedup 1.0000x reference)
//
#include <hip/hip_runtime.h>
#include <hip/hip_fp16.h>

constexpr int N = 200000;
constexpr int E = 5000000;
constexpr int F = 16;
constexpr int BUCKB = 8;         // bucket = dst >> 8 (256 nodes/bucket)
constexpr int NBKT = (N + 255) >> 8;     // 782 -> ~3 blocks/CU in build_csr
constexpr int NB_CH = 512;       // chunk blocks for hist/scatter

// ---- 0: convert x to fp16 ----
__global__ __launch_bounds__(256) void x2h_kernel(const float* __restrict__ x,
                                                  __half* __restrict__ xh) {
    int i = blockIdx.x * 256 + threadIdx.x;
    if (i < N * F / 2) {
        float2 v = reinterpret_cast<const float2*>(x)[i];
        reinterpret_cast<__half2*>(xh)[i] = __floats2half2_rn(v.x, v.y);
    }
}

// ---- 1: per-(bucket, block) histogram of dst ----
__global__ __launch_bounds__(1024) void hist_kernel(const int* __restrict__ dst,
                                                    int* __restrict__ hist) {
    __shared__ int h[NBKT];
    for (int i = threadIdx.x; i < NBKT; i += 1024) h[i] = 0;
    __syncthreads();
    const int chunk = (E + NB_CH - 1) / NB_CH;
    const int lo = blockIdx.x * chunk, hi = min(E, lo + chunk);
    for (int e = lo + (int)threadIdx.x; e < hi; e += 1024)
        atomicAdd(&h[dst[e] >> BUCKB], 1);
    __syncthreads();
    for (int i = threadIdx.x; i < NBKT; i += 1024)
        hist[i * NB_CH + blockIdx.x] = h[i];   // bucket-major
}

// ---- 2: exclusive scan of hist (NBKT*NB_CH ints) in place; extract bucket starts ----
__global__ __launch_bounds__(1024) void scan_hist_kernel(int* __restrict__ hist,
                                                         int* __restrict__ bstart) {
    __shared__ int sm[1024];
    const int M = NBKT * NB_CH;
    const int per = (M + 1023) / 1024;
    const int t = threadIdx.x;
    const int lo = t * per, hi = min(M, lo + per);
    int s = 0;
    for (int i = lo; i < hi; i++) s += hist[i];
    sm[t] = s; __syncthreads();
    for (int st = 1; st < 1024; st <<= 1) {
        int v = (t >= st) ? sm[t - st] : 0;
        __syncthreads();
        sm[t] += v;
        __syncthreads();
    }
    int run = sm[t] - s;                      // exclusive base for this thread's range
    for (int i = lo; i < hi; i++) { int v = hist[i]; hist[i] = run; run += v; }
    __syncthreads();
    for (int i = t; i <= NBKT; i += 1024)
        bstart[i] = (i < NBKT) ? hist[i * NB_CH] : E;
}

// ---- 3: scatter packed (local_dst<<18 | src) into bucket-major order ----
__global__ __launch_bounds__(1024) void bucket_scatter_kernel(const int* __restrict__ src,
                                                              const int* __restrict__ dst,
                                                              const int* __restrict__ hist,
                                                              unsigned* __restrict__ pairs) {
    __shared__ int cur[NBKT];
    for (int i = threadIdx.x; i < NBKT; i += 1024)
        cur[i] = hist[i * NB_CH + blockIdx.x];
    __syncthreads();
    const int chunk = (E + NB_CH - 1) / NB_CH;
    const int lo = blockIdx.x * chunk, hi = min(E, lo + chunk);
    for (int e = lo + (int)threadIdx.x; e < hi; e += 1024) {
        int d = dst[e];
        int p = atomicAdd(&cur[d >> BUCKB], 1);
        pairs[p] = ((unsigned)(d & 255) << 18) | (unsigned)src[e];
    }
}

// ---- 4: per-bucket exact CSR: 256 nodes/bucket, one key per thread ----
__global__ __launch_bounds__(256) void build_csr_kernel(const unsigned* __restrict__ pairs,
                                                        const int* __restrict__ bstart,
                                                        int* __restrict__ off,
                                                        int* __restrict__ col) {
    __shared__ int cnt[256];
    __shared__ int sm[256];
    const int b = blockIdx.x;
    const int p0 = bstart[b], p1 = bstart[b + 1];
    const int nodeBase = b << BUCKB;
    const int t = threadIdx.x;
    cnt[t] = 0;
    __syncthreads();
    for (int j = p0 + t; j < p1; j += 256)
        atomicAdd(&cnt[pairs[j] >> 18], 1);
    __syncthreads();
    // exclusive scan: one key per thread
    int v = cnt[t];
    sm[t] = v; __syncthreads();
    for (int st = 1; st < 256; st <<= 1) {
        int u = (t >= st) ? sm[t - st] : 0;
        __syncthreads();
        sm[t] += u;
        __syncthreads();
    }
    const int start = p0 + sm[t] - v;
    cnt[t] = start;                          // becomes the bump cursor
    const int n = nodeBase + t;
    if (n < N) off[n] = start;
    if (b == gridDim.x - 1 && t == 0) off[N] = p1;
    __syncthreads();
    for (int j = p0 + t; j < p1; j += 256) {
        unsigned pk = pairs[j];
        int p = atomicAdd(&cnt[pk >> 18], 1);
        col[p] = (int)(pk & 0x3FFFF);
    }
}

// ---- fused gather + SAGE update (+optional fc1 / fc2+softmax), fp16 h ----
// block = 256 threads = 16 nodes x 16 feature-lanes; N/16 = 12500 blocks.
// No col staging: each col element is read exactly once (group-broadcast load).
__global__ __launch_bounds__(256) void layer_kernel(
    const __half* __restrict__ hin, __half* __restrict__ hout,
    const int* __restrict__ off, const int* __restrict__ col,
    const float* __restrict__ Wl, const float* __restrict__ bl,
    const float* __restrict__ Wr,
    const float* __restrict__ fcW, const float* __restrict__ fcb,
    int mode,                 // 0 = plain, 1 = +fc1+relu, 2 = final (slice8+fc2+relu+softmax)
    float* __restrict__ outp) {
    __shared__ float Mt[16][17], Xt[16][17];
    const int tid = threadIdx.x;
    const int ty = tid >> 4;
    const int k  = tid & 15;
    const int n  = blockIdx.x * 16 + ty;
    const int o0 = off[n], o1 = off[n + 1];
    const int cnt = o1 - o0;
    const int* __restrict__ cl = col + o0;

    // unroll x8 with independent accumulators -> 8 outstanding gathers per group
    float a0 = 0, a1 = 0, a2 = 0, a3 = 0, a4 = 0, a5 = 0, a6 = 0, a7 = 0;
    int j = 0;
    for (; j + 8 <= cnt; j += 8) {
        int c0 = cl[j],     c1 = cl[j + 1], c2 = cl[j + 2], c3 = cl[j + 3];
        int c4 = cl[j + 4], c5 = cl[j + 5], c6 = cl[j + 6], c7 = cl[j + 7];
        a0 += __half2float(hin[c0 * F + k]); a1 += __half2float(hin[c1 * F + k]);
        a2 += __half2float(hin[c2 * F + k]); a3 += __half2float(hin[c3 * F + k]);
        a4 += __half2float(hin[c4 * F + k]); a5 += __half2float(hin[c5 * F + k]);
        a6 += __half2float(hin[c6 * F + k]); a7 += __half2float(hin[c7 * F + k]);
    }
    for (; j < cnt; j++) a0 += __half2float(hin[cl[j] * F + k]);
    float acc = ((a0 + a1) + (a2 + a3)) + ((a4 + a5) + (a6 + a7));

    const float inv = 1.f / fmaxf((float)cnt, 1.f);
    Mt[ty][k] = acc * inv;
    Xt[ty][k] = __half2float(hin[n * F + k]);
    __syncthreads();

    float a = bl[k];
#pragma unroll
    for (int kk = 0; kk < F; kk++)
        a = fmaf(Mt[ty][kk], Wl[k * F + kk], fmaf(Xt[ty][kk], Wr[k * F + kk], a));
    float o = fmaxf(a, 0.f);   // relu follows every SAGE layer in this graph

    if (mode == 0) { hout[n * F + k] = __float2half(o); return; }

    __syncthreads();
    Mt[ty][k] = o;
    __syncthreads();

    if (mode == 1) {
        float a2f = fcb[k];
#pragma unroll
        for (int kk = 0; kk < F; kk++) a2f = fmaf(Mt[ty][kk], fcW[k * F + kk], a2f);
        hout[n * F + k] = __float2half(fmaxf(a2f, 0.f));
        return;
    }

    // final: slice [:, :8] -> fc2 (8x8) -> relu -> softmax over 8
    if (k < 8) {
        float a2f = fcb[k];
#pragma unroll
        for (int kk = 0; kk < 8; kk++) a2f = fmaf(Mt[ty][kk], fcW[k * 8 + kk], a2f);
        float u = fmaxf(a2f, 0.f);
        float mx = u;
        mx = fmaxf(mx, __shfl_xor(mx, 1));
        mx = fmaxf(mx, __shfl_xor(mx, 2));
        mx = fmaxf(mx, __shfl_xor(mx, 4));
        float ex = __expf(u - mx);
        float sum = ex;
        sum += __shfl_xor(sum, 1);
        sum += __shfl_xor(sum, 2);
        sum += __shfl_xor(sum, 4);
        outp[n * 8 + k] = ex / sum;
    }
}

extern "C" void kernel_launch(void* const* d_in, const int* in_sizes, int n_in,
                              void* d_out, int out_size, void* d_ws, size_t ws_size,
                              hipStream_t stream) {
    const float* x = (const float*)d_in[0];
    const int* edge = (const int*)d_in[1];   // int64 inputs arrive as int32
    const int* src = edge;
    const int* dst = edge + E;
    const float* c1_Wl = (const float*)d_in[2];
    const float* c1_bl = (const float*)d_in[3];
    const float* c1_Wr = (const float*)d_in[4];
    const float* c2_Wl = (const float*)d_in[5];
    const float* c2_bl = (const float*)d_in[6];
    const float* c2_Wr = (const float*)d_in[7];
    const float* fc1_W = (const float*)d_in[8];
    const float* fc1_b = (const float*)d_in[9];
    const float* fc2_W = (const float*)d_in[10];
    const float* fc2_b = (const float*)d_in[11];
    float* out = (float*)d_out;

    // workspace: pairs 20MB + col 20MB + off + hist 1.6MB + xh/hA/hB 19.2MB  (~62MB)
    char* w = (char*)d_ws;
    unsigned* pairs = (unsigned*)w;    w += (size_t)E * 4;
    int* col  = (int*)w;               w += (size_t)E * 4;
    int* off  = (int*)w;               w += (size_t)(N + 4) * 4;
    int* hist = (int*)w;               w += (size_t)NBKT * NB_CH * 4;
    int* bstart = (int*)w;             w += (size_t)(NBKT + 4) * 4;
    __half* xh = (__half*)w;           w += (size_t)N * F * 2;
    __half* hA = (__half*)w;           w += (size_t)N * F * 2;
    __half* hB = (__half*)w;           w += (size_t)N * F * 2;

    const int nblk_nodes = N / 16;                   // 12500

    // ---- CSR build (bucket counting sort; off computed in-bucket) + x fp16 convert ----
    x2h_kernel<<<(N * F / 2 + 255) / 256, 256, 0, stream>>>(x, xh);
    hist_kernel<<<NB_CH, 1024, 0, stream>>>(dst, hist);
    scan_hist_kernel<<<1, 1024, 0, stream>>>(hist, bstart);
    bucket_scatter_kernel<<<NB_CH, 1024, 0, stream>>>(src, dst, hist, pairs);
    build_csr_kernel<<<NBKT, 256, 0, stream>>>(pairs, bstart, off, col);

    // ---- 4 fused layers (ping-pong hA/hB) ----
    layer_kernel<<<nblk_nodes, 256, 0, stream>>>(xh, hA, off, col,
        c1_Wl, c1_bl, c1_Wr, nullptr, nullptr, 0, nullptr);
    layer_kernel<<<nblk_nodes, 256, 0, stream>>>(hA, hB, off, col,
        c1_Wl + F * F, c1_bl + F, c1_Wr + F * F, fc1_W, fc1_b, 1, nullptr);
    layer_kernel<<<nblk_nodes, 256, 0, stream>>>(hB, hA, off, col,
        c2_Wl, c2_bl, c2_Wr, nullptr, nullptr, 0, nullptr);
    layer_kernel<<<nblk_nodes, 256, 0, stream>>>(hA, nullptr, off, col,
        c2_Wl + F * F, c2_bl + F, c2_Wr + F * F, fc2_W, fc2_b, 2, out);
}

// Round 13
// 467.138 us; speedup vs baseline: 1.2720x; 1.2720x over previous
//
#include <hip/hip_runtime.h>
#include <hip/hip_fp16.h>

constexpr int N = 200000;
constexpr int E = 5000000;
constexpr int F = 16;
constexpr int BUCKB = 8;         // bucket = dst >> 8 (256 nodes/bucket)
constexpr int NBKT = (N + 255) >> 8;     // 782 -> ~3 blocks/CU in build_csr
constexpr int NB_CH = 512;       // chunk blocks for hist/scatter

// ---- 0: convert x to fp16 ----
__global__ __launch_bounds__(256) void x2h_kernel(const float* __restrict__ x,
                                                  __half* __restrict__ xh) {
    int i = blockIdx.x * 256 + threadIdx.x;
    if (i < N * F / 2) {
        float2 v = reinterpret_cast<const float2*>(x)[i];
        reinterpret_cast<__half2*>(xh)[i] = __floats2half2_rn(v.x, v.y);
    }
}

// ---- 1: per-(bucket, block) histogram of dst ----
__global__ __launch_bounds__(1024) void hist_kernel(const int* __restrict__ dst,
                                                    int* __restrict__ hist) {
    __shared__ int h[NBKT];
    for (int i = threadIdx.x; i < NBKT; i += 1024) h[i] = 0;
    __syncthreads();
    const int chunk = (E + NB_CH - 1) / NB_CH;
    const int lo = blockIdx.x * chunk, hi = min(E, lo + chunk);
    for (int e = lo + (int)threadIdx.x; e < hi; e += 1024)
        atomicAdd(&h[dst[e] >> BUCKB], 1);
    __syncthreads();
    for (int i = threadIdx.x; i < NBKT; i += 1024)
        hist[i * NB_CH + blockIdx.x] = h[i];   // bucket-major
}

// ---- 2a: per-bucket row sum (NB_CH entries) ----
__global__ __launch_bounds__(256) void scanA_kernel(const int* __restrict__ hist,
                                                    int* __restrict__ rowsum) {
    __shared__ int sm[256];
    const int b = blockIdx.x;
    const int t = threadIdx.x;
    int v = hist[b * NB_CH + t] + hist[b * NB_CH + t + 256];
    sm[t] = v; __syncthreads();
    for (int s = 128; s > 0; s >>= 1) {
        if (t < s) sm[t] += sm[t + s];
        __syncthreads();
    }
    if (t == 0) rowsum[b] = sm[0];
}

// ---- 2b: exclusive scan of rowsum[NBKT] -> rowbase + bstart ----
__global__ __launch_bounds__(1024) void scanB_kernel(const int* __restrict__ rowsum,
                                                     int* __restrict__ rowbase,
                                                     int* __restrict__ bstart) {
    __shared__ int sm[1024];
    const int t = threadIdx.x;
    int v = (t < NBKT) ? rowsum[t] : 0;
    sm[t] = v; __syncthreads();
    for (int st = 1; st < 1024; st <<= 1) {
        int u = (t >= st) ? sm[t - st] : 0;
        __syncthreads();
        sm[t] += u;
        __syncthreads();
    }
    if (t < NBKT) { rowbase[t] = sm[t] - v; bstart[t] = sm[t] - v; }
    if (t == 0) bstart[NBKT] = E;
}

// ---- 2c: exclusive scan within each row (in place) + rowbase ----
__global__ __launch_bounds__(256) void scanC_kernel(int* __restrict__ hist,
                                                    const int* __restrict__ rowbase) {
    __shared__ int sm[256];
    const int b = blockIdx.x;
    const int t = threadIdx.x;
    int v0 = hist[b * NB_CH + 2 * t], v1 = hist[b * NB_CH + 2 * t + 1];
    int s = v0 + v1;
    sm[t] = s; __syncthreads();
    for (int st = 1; st < 256; st <<= 1) {
        int u = (t >= st) ? sm[t - st] : 0;
        __syncthreads();
        sm[t] += u;
        __syncthreads();
    }
    int base = rowbase[b] + sm[t] - s;
    hist[b * NB_CH + 2 * t] = base;
    hist[b * NB_CH + 2 * t + 1] = base + v0;
}

// ---- 3: scatter packed (local_dst<<18 | src) into bucket-major order ----
__global__ __launch_bounds__(1024) void bucket_scatter_kernel(const int* __restrict__ src,
                                                              const int* __restrict__ dst,
                                                              const int* __restrict__ hist,
                                                              unsigned* __restrict__ pairs) {
    __shared__ int cur[NBKT];
    for (int i = threadIdx.x; i < NBKT; i += 1024)
        cur[i] = hist[i * NB_CH + blockIdx.x];
    __syncthreads();
    const int chunk = (E + NB_CH - 1) / NB_CH;
    const int lo = blockIdx.x * chunk, hi = min(E, lo + chunk);
    for (int e = lo + (int)threadIdx.x; e < hi; e += 1024) {
        int d = dst[e];
        int p = atomicAdd(&cur[d >> BUCKB], 1);
        pairs[p] = ((unsigned)(d & 255) << 18) | (unsigned)src[e];
    }
}

// ---- 4: per-bucket exact CSR: 256 nodes/bucket, one key per thread ----
__global__ __launch_bounds__(256) void build_csr_kernel(const unsigned* __restrict__ pairs,
                                                        const int* __restrict__ bstart,
                                                        int* __restrict__ off,
                                                        int* __restrict__ col) {
    __shared__ int cnt[256];
    __shared__ int sm[256];
    const int b = blockIdx.x;
    const int p0 = bstart[b], p1 = bstart[b + 1];
    const int nodeBase = b << BUCKB;
    const int t = threadIdx.x;
    cnt[t] = 0;
    __syncthreads();
    for (int j = p0 + t; j < p1; j += 256)
        atomicAdd(&cnt[pairs[j] >> 18], 1);
    __syncthreads();
    int v = cnt[t];
    sm[t] = v; __syncthreads();
    for (int st = 1; st < 256; st <<= 1) {
        int u = (t >= st) ? sm[t - st] : 0;
        __syncthreads();
        sm[t] += u;
        __syncthreads();
    }
    const int start = p0 + sm[t] - v;
    cnt[t] = start;                          // becomes the bump cursor
    const int n = nodeBase + t;
    if (n < N) off[n] = start;
    if (b == gridDim.x - 1 && t == 0) off[N] = p1;
    __syncthreads();
    for (int j = p0 + t; j < p1; j += 256) {
        unsigned pk = pairs[j];
        int p = atomicAdd(&cnt[pk >> 18], 1);
        col[p] = (int)(pk & 0x3FFFF);
    }
}

// ---- fused gather + SAGE update (+optional fc1 / fc2+softmax), fp16 h ----
// block = 256 threads = 16 nodes x 16 feature-lanes; N/16 = 12500 blocks.
__global__ __launch_bounds__(256) void layer_kernel(
    const __half* __restrict__ hin, __half* __restrict__ hout,
    const int* __restrict__ off, const int* __restrict__ col,
    const float* __restrict__ Wl, const float* __restrict__ bl,
    const float* __restrict__ Wr,
    const float* __restrict__ fcW, const float* __restrict__ fcb,
    int mode,                 // 0 = plain, 1 = +fc1+relu, 2 = final (slice8+fc2+relu+softmax)
    float* __restrict__ outp) {
    __shared__ float Mt[16][17], Xt[16][17];
    const int tid = threadIdx.x;
    const int ty = tid >> 4;
    const int k  = tid & 15;
    const int n  = blockIdx.x * 16 + ty;
    const int o0 = off[n], o1 = off[n + 1];
    const int cnt = o1 - o0;
    const int* __restrict__ cl = col + o0;

    // unroll x8 with independent accumulators -> 8 outstanding gathers per group
    float a0 = 0, a1 = 0, a2 = 0, a3 = 0, a4 = 0, a5 = 0, a6 = 0, a7 = 0;
    int j = 0;
    for (; j + 8 <= cnt; j += 8) {
        int c0 = cl[j],     c1 = cl[j + 1], c2 = cl[j + 2], c3 = cl[j + 3];
        int c4 = cl[j + 4], c5 = cl[j + 5], c6 = cl[j + 6], c7 = cl[j + 7];
        a0 += __half2float(hin[c0 * F + k]); a1 += __half2float(hin[c1 * F + k]);
        a2 += __half2float(hin[c2 * F + k]); a3 += __half2float(hin[c3 * F + k]);
        a4 += __half2float(hin[c4 * F + k]); a5 += __half2float(hin[c5 * F + k]);
        a6 += __half2float(hin[c6 * F + k]); a7 += __half2float(hin[c7 * F + k]);
    }
    for (; j < cnt; j++) a0 += __half2float(hin[cl[j] * F + k]);
    float acc = ((a0 + a1) + (a2 + a3)) + ((a4 + a5) + (a6 + a7));

    const float inv = 1.f / fmaxf((float)cnt, 1.f);
    Mt[ty][k] = acc * inv;
    Xt[ty][k] = __half2float(hin[n * F + k]);
    __syncthreads();

    float a = bl[k];
#pragma unroll
    for (int kk = 0; kk < F; kk++)
        a = fmaf(Mt[ty][kk], Wl[k * F + kk], fmaf(Xt[ty][kk], Wr[k * F + kk], a));
    float o = fmaxf(a, 0.f);   // relu follows every SAGE layer in this graph

    if (mode == 0) { hout[n * F + k] = __float2half(o); return; }

    __syncthreads();
    Mt[ty][k] = o;
    __syncthreads();

    if (mode == 1) {
        float a2f = fcb[k];
#pragma unroll
        for (int kk = 0; kk < F; kk++) a2f = fmaf(Mt[ty][kk], fcW[k * F + kk], a2f);
        hout[n * F + k] = __float2half(fmaxf(a2f, 0.f));
        return;
    }

    // final: slice [:, :8] -> fc2 (8x8) -> relu -> softmax over 8
    if (k < 8) {
        float a2f = fcb[k];
#pragma unroll
        for (int kk = 0; kk < 8; kk++) a2f = fmaf(Mt[ty][kk], fcW[k * 8 + kk], a2f);
        float u = fmaxf(a2f, 0.f);
        float mx = u;
        mx = fmaxf(mx, __shfl_xor(mx, 1));
        mx = fmaxf(mx, __shfl_xor(mx, 2));
        mx = fmaxf(mx, __shfl_xor(mx, 4));
        float ex = __expf(u - mx);
        float sum = ex;
        sum += __shfl_xor(sum, 1);
        sum += __shfl_xor(sum, 2);
        sum += __shfl_xor(sum, 4);
        outp[n * 8 + k] = ex / sum;
    }
}

extern "C" void kernel_launch(void* const* d_in, const int* in_sizes, int n_in,
                              void* d_out, int out_size, void* d_ws, size_t ws_size,
                              hipStream_t stream) {
    const float* x = (const float*)d_in[0];
    const int* edge = (const int*)d_in[1];   // int64 inputs arrive as int32
    const int* src = edge;
    const int* dst = edge + E;
    const float* c1_Wl = (const float*)d_in[2];
    const float* c1_bl = (const float*)d_in[3];
    const float* c1_Wr = (const float*)d_in[4];
    const float* c2_Wl = (const float*)d_in[5];
    const float* c2_bl = (const float*)d_in[6];
    const float* c2_Wr = (const float*)d_in[7];
    const float* fc1_W = (const float*)d_in[8];
    const float* fc1_b = (const float*)d_in[9];
    const float* fc2_W = (const float*)d_in[10];
    const float* fc2_b = (const float*)d_in[11];
    float* out = (float*)d_out;

    // workspace: pairs 20MB + col 20MB + off + hist 1.6MB + scan tmps + xh/hA/hB 19.2MB
    char* w = (char*)d_ws;
    unsigned* pairs = (unsigned*)w;    w += (size_t)E * 4;
    int* col  = (int*)w;               w += (size_t)E * 4;
    int* off  = (int*)w;               w += (size_t)(N + 4) * 4;
    int* hist = (int*)w;               w += (size_t)NBKT * NB_CH * 4;
    int* bstart = (int*)w;             w += (size_t)(NBKT + 4) * 4;
    int* rowsum = (int*)w;             w += (size_t)(NBKT + 4) * 4;
    int* rowbase = (int*)w;            w += (size_t)(NBKT + 4) * 4;
    __half* xh = (__half*)w;           w += (size_t)N * F * 2;
    __half* hA = (__half*)w;           w += (size_t)N * F * 2;
    __half* hB = (__half*)w;           w += (size_t)N * F * 2;

    const int nblk_nodes = N / 16;                   // 12500

    // ---- CSR build (bucket counting sort; hierarchical scan) + x fp16 convert ----
    x2h_kernel<<<(N * F / 2 + 255) / 256, 256, 0, stream>>>(x, xh);
    hist_kernel<<<NB_CH, 1024, 0, stream>>>(dst, hist);
    scanA_kernel<<<NBKT, 256, 0, stream>>>(hist, rowsum);
    scanB_kernel<<<1, 1024, 0, stream>>>(rowsum, rowbase, bstart);
    scanC_kernel<<<NBKT, 256, 0, stream>>>(hist, rowbase);
    bucket_scatter_kernel<<<NB_CH, 1024, 0, stream>>>(src, dst, hist, pairs);
    build_csr_kernel<<<NBKT, 256, 0, stream>>>(pairs, bstart, off, col);

    // ---- 4 fused layers (ping-pong hA/hB) ----
    layer_kernel<<<nblk_nodes, 256, 0, stream>>>(xh, hA, off, col,
        c1_Wl, c1_bl, c1_Wr, nullptr, nullptr, 0, nullptr);
    layer_kernel<<<nblk_nodes, 256, 0, stream>>>(hA, hB, off, col,
        c1_Wl + F * F, c1_bl + F, c1_Wr + F * F, fc1_W, fc1_b, 1, nullptr);
    layer_kernel<<<nblk_nodes, 256, 0, stream>>>(hB, hA, off, col,
        c2_Wl, c2_bl, c2_Wr, nullptr, nullptr, 0, nullptr);
    layer_kernel<<<nblk_nodes, 256, 0, stream>>>(hA, nullptr, off, col,
        c2_Wl + F * F, c2_bl + F, c2_Wr + F * F, fc2_W, fc2_b, 2, out);
}

// Round 14
// 408.230 us; speedup vs baseline: 1.4556x; 1.1443x over previous
//
#include <hip/hip_runtime.h>
#include <hip/hip_fp16.h>

constexpr int N = 200000;
constexpr int E = 5000000;
constexpr int F = 16;
constexpr int CAP = 2048;        // LDS col staging per layer block
constexpr int BUCKB = 8;         // bucket = dst >> 8 (256 nodes/bucket)
constexpr int NBKT = (N + 255) >> 8;     // 782 -> ~3 blocks/CU in build_csr
constexpr int NB_CH = 512;       // chunk blocks for hist/scatter

// ---- 0: convert x to fp16 ----
__global__ __launch_bounds__(256) void x2h_kernel(const float* __restrict__ x,
                                                  __half* __restrict__ xh) {
    int i = blockIdx.x * 256 + threadIdx.x;
    if (i < N * F / 2) {
        float2 v = reinterpret_cast<const float2*>(x)[i];
        reinterpret_cast<__half2*>(xh)[i] = __floats2half2_rn(v.x, v.y);
    }
}

// ---- 1: per-(bucket, block) histogram of dst ----
__global__ __launch_bounds__(1024) void hist_kernel(const int* __restrict__ dst,
                                                    int* __restrict__ hist) {
    __shared__ int h[NBKT];
    for (int i = threadIdx.x; i < NBKT; i += 1024) h[i] = 0;
    __syncthreads();
    const int chunk = (E + NB_CH - 1) / NB_CH;
    const int lo = blockIdx.x * chunk, hi = min(E, lo + chunk);
    for (int e = lo + (int)threadIdx.x; e < hi; e += 1024)
        atomicAdd(&h[dst[e] >> BUCKB], 1);
    __syncthreads();
    for (int i = threadIdx.x; i < NBKT; i += 1024)
        hist[i * NB_CH + blockIdx.x] = h[i];   // bucket-major
}

// ---- 2a: per-bucket row sum (NB_CH entries) ----
__global__ __launch_bounds__(256) void scanA_kernel(const int* __restrict__ hist,
                                                    int* __restrict__ rowsum) {
    __shared__ int sm[256];
    const int b = blockIdx.x;
    const int t = threadIdx.x;
    int v = hist[b * NB_CH + t] + hist[b * NB_CH + t + 256];
    sm[t] = v; __syncthreads();
    for (int s = 128; s > 0; s >>= 1) {
        if (t < s) sm[t] += sm[t + s];
        __syncthreads();
    }
    if (t == 0) rowsum[b] = sm[0];
}

// ---- 2b: exclusive scan of rowsum[NBKT] -> rowbase + bstart ----
__global__ __launch_bounds__(1024) void scanB_kernel(const int* __restrict__ rowsum,
                                                     int* __restrict__ rowbase,
                                                     int* __restrict__ bstart) {
    __shared__ int sm[1024];
    const int t = threadIdx.x;
    int v = (t < NBKT) ? rowsum[t] : 0;
    sm[t] = v; __syncthreads();
    for (int st = 1; st < 1024; st <<= 1) {
        int u = (t >= st) ? sm[t - st] : 0;
        __syncthreads();
        sm[t] += u;
        __syncthreads();
    }
    if (t < NBKT) { rowbase[t] = sm[t] - v; bstart[t] = sm[t] - v; }
    if (t == 0) bstart[NBKT] = E;
}

// ---- 2c: exclusive scan within each row (in place) + rowbase ----
__global__ __launch_bounds__(256) void scanC_kernel(int* __restrict__ hist,
                                                    const int* __restrict__ rowbase) {
    __shared__ int sm[256];
    const int b = blockIdx.x;
    const int t = threadIdx.x;
    int v0 = hist[b * NB_CH + 2 * t], v1 = hist[b * NB_CH + 2 * t + 1];
    int s = v0 + v1;
    sm[t] = s; __syncthreads();
    for (int st = 1; st < 256; st <<= 1) {
        int u = (t >= st) ? sm[t - st] : 0;
        __syncthreads();
        sm[t] += u;
        __syncthreads();
    }
    int base = rowbase[b] + sm[t] - s;
    hist[b * NB_CH + 2 * t] = base;
    hist[b * NB_CH + 2 * t + 1] = base + v0;
}

// ---- 3: scatter packed (local_dst<<18 | src) into bucket-major order ----
__global__ __launch_bounds__(1024) void bucket_scatter_kernel(const int* __restrict__ src,
                                                              const int* __restrict__ dst,
                                                              const int* __restrict__ hist,
                                                              unsigned* __restrict__ pairs) {
    __shared__ int cur[NBKT];
    for (int i = threadIdx.x; i < NBKT; i += 1024)
        cur[i] = hist[i * NB_CH + blockIdx.x];
    __syncthreads();
    const int chunk = (E + NB_CH - 1) / NB_CH;
    const int lo = blockIdx.x * chunk, hi = min(E, lo + chunk);
    for (int e = lo + (int)threadIdx.x; e < hi; e += 1024) {
        int d = dst[e];
        int p = atomicAdd(&cur[d >> BUCKB], 1);
        pairs[p] = ((unsigned)(d & 255) << 18) | (unsigned)src[e];
    }
}

// ---- 4: per-bucket exact CSR: 256 nodes/bucket, one key per thread ----
__global__ __launch_bounds__(256) void build_csr_kernel(const unsigned* __restrict__ pairs,
                                                        const int* __restrict__ bstart,
                                                        int* __restrict__ off,
                                                        int* __restrict__ col) {
    __shared__ int cnt[256];
    __shared__ int sm[256];
    const int b = blockIdx.x;
    const int p0 = bstart[b], p1 = bstart[b + 1];
    const int nodeBase = b << BUCKB;
    const int t = threadIdx.x;
    cnt[t] = 0;
    __syncthreads();
    for (int j = p0 + t; j < p1; j += 256)
        atomicAdd(&cnt[pairs[j] >> 18], 1);
    __syncthreads();
    int v = cnt[t];
    sm[t] = v; __syncthreads();
    for (int st = 1; st < 256; st <<= 1) {
        int u = (t >= st) ? sm[t - st] : 0;
        __syncthreads();
        sm[t] += u;
        __syncthreads();
    }
    const int start = p0 + sm[t] - v;
    cnt[t] = start;                          // becomes the bump cursor
    const int n = nodeBase + t;
    if (n < N) off[n] = start;
    if (b == gridDim.x - 1 && t == 0) off[N] = p1;
    __syncthreads();
    for (int j = p0 + t; j < p1; j += 256) {
        unsigned pk = pairs[j];
        int p = atomicAdd(&cnt[pk >> 18], 1);
        col[p] = (int)(pk & 0x3FFFF);
    }
}

// ---- fused gather + SAGE update (+optional fc1 / fc2+softmax), fp16 h ----
// block = 256 threads = 16 nodes x 16 feature-lanes; N/16 = 12500 blocks.
// LDS col staging amortizes col read into one coalesced burst (measured 80.6us).
__global__ __launch_bounds__(256) void layer_kernel(
    const __half* __restrict__ hin, __half* __restrict__ hout,
    const int* __restrict__ off, const int* __restrict__ col,
    const float* __restrict__ Wl, const float* __restrict__ bl,
    const float* __restrict__ Wr,
    const float* __restrict__ fcW, const float* __restrict__ fcb,
    int mode,                 // 0 = plain, 1 = +fc1+relu, 2 = final (slice8+fc2+relu+softmax)
    float* __restrict__ outp) {
    __shared__ int cols[CAP];
    __shared__ float Mt[16][17], Xt[16][17];
    const int tid = threadIdx.x;
    const int nb = blockIdx.x * 16;
    const int base = off[nb];
    const int tot = off[nb + 16] - base;
    const int stot = min(tot, CAP);
    for (int j = tid; j < stot; j += 256)           // coalesced stage of block's col range
        cols[j] = col[base + j];
    __syncthreads();

    const int ty = tid >> 4;
    const int k  = tid & 15;
    const int n  = nb + ty;
    const int o0 = off[n] - base, o1 = off[n + 1] - base;

    // unroll x8 with independent accumulators -> 8 outstanding gathers per group
    float a0 = 0, a1 = 0, a2 = 0, a3 = 0, a4 = 0, a5 = 0, a6 = 0, a7 = 0;
    const int lim = min(o1, CAP);
    int j = o0;
    for (; j + 8 <= lim; j += 8) {
        int c0 = cols[j],     c1 = cols[j + 1], c2 = cols[j + 2], c3 = cols[j + 3];
        int c4 = cols[j + 4], c5 = cols[j + 5], c6 = cols[j + 6], c7 = cols[j + 7];
        a0 += __half2float(hin[c0 * F + k]); a1 += __half2float(hin[c1 * F + k]);
        a2 += __half2float(hin[c2 * F + k]); a3 += __half2float(hin[c3 * F + k]);
        a4 += __half2float(hin[c4 * F + k]); a5 += __half2float(hin[c5 * F + k]);
        a6 += __half2float(hin[c6 * F + k]); a7 += __half2float(hin[c7 * F + k]);
    }
    for (; j < lim; j++) a0 += __half2float(hin[cols[j] * F + k]);
    for (; j < o1; j++)  a0 += __half2float(hin[col[base + j] * F + k]);  // CAP overflow
    float acc = ((a0 + a1) + (a2 + a3)) + ((a4 + a5) + (a6 + a7));

    const float inv = 1.f / fmaxf((float)(o1 - o0), 1.f);
    Mt[ty][k] = acc * inv;
    Xt[ty][k] = __half2float(hin[n * F + k]);
    __syncthreads();

    float a = bl[k];
#pragma unroll
    for (int kk = 0; kk < F; kk++)
        a = fmaf(Mt[ty][kk], Wl[k * F + kk], fmaf(Xt[ty][kk], Wr[k * F + kk], a));
    float o = fmaxf(a, 0.f);   // relu follows every SAGE layer in this graph

    if (mode == 0) { hout[n * F + k] = __float2half(o); return; }

    __syncthreads();
    Mt[ty][k] = o;
    __syncthreads();

    if (mode == 1) {
        float a2f = fcb[k];
#pragma unroll
        for (int kk = 0; kk < F; kk++) a2f = fmaf(Mt[ty][kk], fcW[k * F + kk], a2f);
        hout[n * F + k] = __float2half(fmaxf(a2f, 0.f));
        return;
    }

    // final: slice [:, :8] -> fc2 (8x8) -> relu -> softmax over 8
    if (k < 8) {
        float a2f = fcb[k];
#pragma unroll
        for (int kk = 0; kk < 8; kk++) a2f = fmaf(Mt[ty][kk], fcW[k * 8 + kk], a2f);
        float u = fmaxf(a2f, 0.f);
        float mx = u;
        mx = fmaxf(mx, __shfl_xor(mx, 1));
        mx = fmaxf(mx, __shfl_xor(mx, 2));
        mx = fmaxf(mx, __shfl_xor(mx, 4));
        float ex = __expf(u - mx);
        float sum = ex;
        sum += __shfl_xor(sum, 1);
        sum += __shfl_xor(sum, 2);
        sum += __shfl_xor(sum, 4);
        outp[n * 8 + k] = ex / sum;
    }
}

extern "C" void kernel_launch(void* const* d_in, const int* in_sizes, int n_in,
                              void* d_out, int out_size, void* d_ws, size_t ws_size,
                              hipStream_t stream) {
    const float* x = (const float*)d_in[0];
    const int* edge = (const int*)d_in[1];   // int64 inputs arrive as int32
    const int* src = edge;
    const int* dst = edge + E;
    const float* c1_Wl = (const float*)d_in[2];
    const float* c1_bl = (const float*)d_in[3];
    const float* c1_Wr = (const float*)d_in[4];
    const float* c2_Wl = (const float*)d_in[5];
    const float* c2_bl = (const float*)d_in[6];
    const float* c2_Wr = (const float*)d_in[7];
    const float* fc1_W = (const float*)d_in[8];
    const float* fc1_b = (const float*)d_in[9];
    const float* fc2_W = (const float*)d_in[10];
    const float* fc2_b = (const float*)d_in[11];
    float* out = (float*)d_out;

    // workspace: pairs 20MB + col 20MB + off + hist 1.6MB + scan tmps + xh/hA/hB 19.2MB
    char* w = (char*)d_ws;
    unsigned* pairs = (unsigned*)w;    w += (size_t)E * 4;
    int* col  = (int*)w;               w += (size_t)E * 4;
    int* off  = (int*)w;               w += (size_t)(N + 4) * 4;
    int* hist = (int*)w;               w += (size_t)NBKT * NB_CH * 4;
    int* bstart = (int*)w;             w += (size_t)(NBKT + 4) * 4;
    int* rowsum = (int*)w;             w += (size_t)(NBKT + 4) * 4;
    int* rowbase = (int*)w;            w += (size_t)(NBKT + 4) * 4;
    __half* xh = (__half*)w;           w += (size_t)N * F * 2;
    __half* hA = (__half*)w;           w += (size_t)N * F * 2;
    __half* hB = (__half*)w;           w += (size_t)N * F * 2;

    const int nblk_nodes = N / 16;                   // 12500

    // ---- CSR build (bucket counting sort; hierarchical scan) + x fp16 convert ----
    x2h_kernel<<<(N * F / 2 + 255) / 256, 256, 0, stream>>>(x, xh);
    hist_kernel<<<NB_CH, 1024, 0, stream>>>(dst, hist);
    scanA_kernel<<<NBKT, 256, 0, stream>>>(hist, rowsum);
    scanB_kernel<<<1, 1024, 0, stream>>>(rowsum, rowbase, bstart);
    scanC_kernel<<<NBKT, 256, 0, stream>>>(hist, rowbase);
    bucket_scatter_kernel<<<NB_CH, 1024, 0, stream>>>(src, dst, hist, pairs);
    build_csr_kernel<<<NBKT, 256, 0, stream>>>(pairs, bstart, off, col);

    // ---- 4 fused layers (ping-pong hA/hB) ----
    layer_kernel<<<nblk_nodes, 256, 0, stream>>>(xh, hA, off, col,
        c1_Wl, c1_bl, c1_Wr, nullptr, nullptr, 0, nullptr);
    layer_kernel<<<nblk_nodes, 256, 0, stream>>>(hA, hB, off, col,
        c1_Wl + F * F, c1_bl + F, c1_Wr + F * F, fc1_W, fc1_b, 1, nullptr);
    layer_kernel<<<nblk_nodes, 256, 0, stream>>>(hB, hA, off, col,
        c2_Wl, c2_bl, c2_Wr, nullptr, nullptr, 0, nullptr);
    layer_kernel<<<nblk_nodes, 256, 0, stream>>>(hA, nullptr, off, col,
        c2_Wl + F * F, c2_bl + F, c2_Wr + F * F, fc2_W, fc2_b, 2, out);
}

// Round 15
// 406.920 us; speedup vs baseline: 1.4603x; 1.0032x over previous
//
#include <hip/hip_runtime.h>
#include <hip/hip_fp16.h>

constexpr int N = 200000;
constexpr int E = 5000000;
constexpr int F = 16;
constexpr int CAP = 2048;        // LDS col staging per layer block
constexpr int BUCKB = 10;        // bucket = dst >> 10 (1024 nodes/bucket)
constexpr int NBKT = (N + 1023) >> 10;   // 196
constexpr int NB_CH = 256;       // chunk blocks for hist/scatter (runs ~100 edges = 400B)

// ---- 0: convert x to fp16 ----
__global__ __launch_bounds__(256) void x2h_kernel(const float* __restrict__ x,
                                                  __half* __restrict__ xh) {
    int i = blockIdx.x * 256 + threadIdx.x;
    if (i < N * F / 2) {
        float2 v = reinterpret_cast<const float2*>(x)[i];
        reinterpret_cast<__half2*>(xh)[i] = __floats2half2_rn(v.x, v.y);
    }
}

// ---- 1: per-(bucket, block) histogram of dst ----
__global__ __launch_bounds__(1024) void hist_kernel(const int* __restrict__ dst,
                                                    int* __restrict__ hist) {
    __shared__ int h[NBKT];
    if (threadIdx.x < NBKT) h[threadIdx.x] = 0;
    __syncthreads();
    const int chunk = (E + NB_CH - 1) / NB_CH;
    const int lo = blockIdx.x * chunk, hi = min(E, lo + chunk);
    for (int e = lo + (int)threadIdx.x; e < hi; e += 1024)
        atomicAdd(&h[dst[e] >> BUCKB], 1);
    __syncthreads();
    if (threadIdx.x < NBKT)
        hist[threadIdx.x * NB_CH + blockIdx.x] = h[threadIdx.x];   // bucket-major
}

// ---- 2a: per-bucket row sum (NB_CH = 256 entries, one per thread) ----
__global__ __launch_bounds__(256) void scanA_kernel(const int* __restrict__ hist,
                                                    int* __restrict__ rowsum) {
    __shared__ int sm[256];
    const int b = blockIdx.x;
    const int t = threadIdx.x;
    sm[t] = hist[b * NB_CH + t]; __syncthreads();
    for (int s = 128; s > 0; s >>= 1) {
        if (t < s) sm[t] += sm[t + s];
        __syncthreads();
    }
    if (t == 0) rowsum[b] = sm[0];
}

// ---- 2b: exclusive scan of rowsum[NBKT] -> rowbase + bstart ----
__global__ __launch_bounds__(256) void scanB_kernel(const int* __restrict__ rowsum,
                                                    int* __restrict__ rowbase,
                                                    int* __restrict__ bstart) {
    __shared__ int sm[256];
    const int t = threadIdx.x;
    int v = (t < NBKT) ? rowsum[t] : 0;
    sm[t] = v; __syncthreads();
    for (int st = 1; st < 256; st <<= 1) {
        int u = (t >= st) ? sm[t - st] : 0;
        __syncthreads();
        sm[t] += u;
        __syncthreads();
    }
    if (t < NBKT) { rowbase[t] = sm[t] - v; bstart[t] = sm[t] - v; }
    if (t == 0) bstart[NBKT] = E;
}

// ---- 2c: exclusive scan within each row (in place) + rowbase ----
__global__ __launch_bounds__(256) void scanC_kernel(int* __restrict__ hist,
                                                    const int* __restrict__ rowbase) {
    __shared__ int sm[256];
    const int b = blockIdx.x;
    const int t = threadIdx.x;
    int v = hist[b * NB_CH + t];
    sm[t] = v; __syncthreads();
    for (int st = 1; st < 256; st <<= 1) {
        int u = (t >= st) ? sm[t - st] : 0;
        __syncthreads();
        sm[t] += u;
        __syncthreads();
    }
    hist[b * NB_CH + t] = rowbase[b] + sm[t] - v;
}

// ---- 3: scatter packed (local_dst<<18 | src) into bucket-major order ----
__global__ __launch_bounds__(1024) void bucket_scatter_kernel(const int* __restrict__ src,
                                                              const int* __restrict__ dst,
                                                              const int* __restrict__ hist,
                                                              unsigned* __restrict__ pairs) {
    __shared__ int cur[NBKT];
    if (threadIdx.x < NBKT) cur[threadIdx.x] = hist[threadIdx.x * NB_CH + blockIdx.x];
    __syncthreads();
    const int chunk = (E + NB_CH - 1) / NB_CH;
    const int lo = blockIdx.x * chunk, hi = min(E, lo + chunk);
    for (int e = lo + (int)threadIdx.x; e < hi; e += 1024) {
        int d = dst[e];
        int p = atomicAdd(&cur[d >> BUCKB], 1);
        pairs[p] = ((unsigned)(d & 1023) << 18) | (unsigned)src[e];
    }
}

// ---- 4: per-bucket exact CSR: 1024 nodes/bucket, 4 keys per thread ----
__global__ __launch_bounds__(256) void build_csr_kernel(const unsigned* __restrict__ pairs,
                                                        const int* __restrict__ bstart,
                                                        int* __restrict__ off,
                                                        int* __restrict__ col) {
    __shared__ int cnt[1024];
    __shared__ int sm[256];
    const int b = blockIdx.x;
    const int p0 = bstart[b], p1 = bstart[b + 1];
    const int nodeBase = b << BUCKB;
    const int t = threadIdx.x;
    for (int i = t; i < 1024; i += 256) cnt[i] = 0;
    __syncthreads();
    for (int j = p0 + t; j < p1; j += 256)
        atomicAdd(&cnt[pairs[j] >> 18], 1);
    __syncthreads();
    int c0 = cnt[4 * t], c1 = cnt[4 * t + 1], c2 = cnt[4 * t + 2], c3 = cnt[4 * t + 3];
    int s = c0 + c1 + c2 + c3;
    sm[t] = s; __syncthreads();
    for (int st = 1; st < 256; st <<= 1) {
        int u = (t >= st) ? sm[t - st] : 0;
        __syncthreads();
        sm[t] += u;
        __syncthreads();
    }
    const int abs0 = p0 + sm[t] - s;
    cnt[4 * t] = abs0;
    cnt[4 * t + 1] = abs0 + c0;
    cnt[4 * t + 2] = abs0 + c0 + c1;
    cnt[4 * t + 3] = abs0 + c0 + c1 + c2;
    const int n0 = nodeBase + 4 * t;
#pragma unroll
    for (int q = 0; q < 4; q++)
        if (n0 + q < N) off[n0 + q] = cnt[4 * t + q];
    if (b == gridDim.x - 1 && t == 255) off[N] = p1;
    __syncthreads();
    for (int j = p0 + t; j < p1; j += 256) {
        unsigned pk = pairs[j];
        int p = atomicAdd(&cnt[pk >> 18], 1);
        col[p] = (int)(pk & 0x3FFFF);
    }
}

// ---- fused gather + SAGE update (+optional fc1 / fc2+softmax), fp16 h ----
// block = 256 threads = 16 nodes x 16 feature-lanes; N/16 = 12500 blocks.
// LDS col staging amortizes col read into one coalesced burst (measured 80.6us).
__global__ __launch_bounds__(256) void layer_kernel(
    const __half* __restrict__ hin, __half* __restrict__ hout,
    const int* __restrict__ off, const int* __restrict__ col,
    const float* __restrict__ Wl, const float* __restrict__ bl,
    const float* __restrict__ Wr,
    const float* __restrict__ fcW, const float* __restrict__ fcb,
    int mode,                 // 0 = plain, 1 = +fc1+relu, 2 = final (slice8+fc2+relu+softmax)
    float* __restrict__ outp) {
    __shared__ int cols[CAP];
    __shared__ float Mt[16][17], Xt[16][17];
    const int tid = threadIdx.x;
    const int nb = blockIdx.x * 16;
    const int base = off[nb];
    const int tot = off[nb + 16] - base;
    const int stot = min(tot, CAP);
    for (int j = tid; j < stot; j += 256)           // coalesced stage of block's col range
        cols[j] = col[base + j];
    __syncthreads();

    const int ty = tid >> 4;
    const int k  = tid & 15;
    const int n  = nb + ty;
    const int o0 = off[n] - base, o1 = off[n + 1] - base;

    // unroll x8 with independent accumulators -> 8 outstanding gathers per group
    float a0 = 0, a1 = 0, a2 = 0, a3 = 0, a4 = 0, a5 = 0, a6 = 0, a7 = 0;
    const int lim = min(o1, CAP);
    int j = o0;
    for (; j + 8 <= lim; j += 8) {
        int c0 = cols[j],     c1 = cols[j + 1], c2 = cols[j + 2], c3 = cols[j + 3];
        int c4 = cols[j + 4], c5 = cols[j + 5], c6 = cols[j + 6], c7 = cols[j + 7];
        a0 += __half2float(hin[c0 * F + k]); a1 += __half2float(hin[c1 * F + k]);
        a2 += __half2float(hin[c2 * F + k]); a3 += __half2float(hin[c3 * F + k]);
        a4 += __half2float(hin[c4 * F + k]); a5 += __half2float(hin[c5 * F + k]);
        a6 += __half2float(hin[c6 * F + k]); a7 += __half2float(hin[c7 * F + k]);
    }
    for (; j < lim; j++) a0 += __half2float(hin[cols[j] * F + k]);
    for (; j < o1; j++)  a0 += __half2float(hin[col[base + j] * F + k]);  // CAP overflow
    float acc = ((a0 + a1) + (a2 + a3)) + ((a4 + a5) + (a6 + a7));

    const float inv = 1.f / fmaxf((float)(o1 - o0), 1.f);
    Mt[ty][k] = acc * inv;
    Xt[ty][k] = __half2float(hin[n * F + k]);
    __syncthreads();

    float a = bl[k];
#pragma unroll
    for (int kk = 0; kk < F; kk++)
        a = fmaf(Mt[ty][kk], Wl[k * F + kk], fmaf(Xt[ty][kk], Wr[k * F + kk], a));
    float o = fmaxf(a, 0.f);   // relu follows every SAGE layer in this graph

    if (mode == 0) { hout[n * F + k] = __float2half(o); return; }

    __syncthreads();
    Mt[ty][k] = o;
    __syncthreads();

    if (mode == 1) {
        float a2f = fcb[k];
#pragma unroll
        for (int kk = 0; kk < F; kk++) a2f = fmaf(Mt[ty][kk], fcW[k * F + kk], a2f);
        hout[n * F + k] = __float2half(fmaxf(a2f, 0.f));
        return;
    }

    // final: slice [:, :8] -> fc2 (8x8) -> relu -> softmax over 8
    if (k < 8) {
        float a2f = fcb[k];
#pragma unroll
        for (int kk = 0; kk < 8; kk++) a2f = fmaf(Mt[ty][kk], fcW[k * 8 + kk], a2f);
        float u = fmaxf(a2f, 0.f);
        float mx = u;
        mx = fmaxf(mx, __shfl_xor(mx, 1));
        mx = fmaxf(mx, __shfl_xor(mx, 2));
        mx = fmaxf(mx, __shfl_xor(mx, 4));
        float ex = __expf(u - mx);
        float sum = ex;
        sum += __shfl_xor(sum, 1);
        sum += __shfl_xor(sum, 2);
        sum += __shfl_xor(sum, 4);
        outp[n * 8 + k] = ex / sum;
    }
}

extern "C" void kernel_launch(void* const* d_in, const int* in_sizes, int n_in,
                              void* d_out, int out_size, void* d_ws, size_t ws_size,
                              hipStream_t stream) {
    const float* x = (const float*)d_in[0];
    const int* edge = (const int*)d_in[1];   // int64 inputs arrive as int32
    const int* src = edge;
    const int* dst = edge + E;
    const float* c1_Wl = (const float*)d_in[2];
    const float* c1_bl = (const float*)d_in[3];
    const float* c1_Wr = (const float*)d_in[4];
    const float* c2_Wl = (const float*)d_in[5];
    const float* c2_bl = (const float*)d_in[6];
    const float* c2_Wr = (const float*)d_in[7];
    const float* fc1_W = (const float*)d_in[8];
    const float* fc1_b = (const float*)d_in[9];
    const float* fc2_W = (const float*)d_in[10];
    const float* fc2_b = (const float*)d_in[11];
    float* out = (float*)d_out;

    // workspace: pairs 20MB + col 20MB + off + hist 200KB + scan tmps + xh/hA/hB 19.2MB
    char* w = (char*)d_ws;
    unsigned* pairs = (unsigned*)w;    w += (size_t)E * 4;
    int* col  = (int*)w;               w += (size_t)E * 4;
    int* off  = (int*)w;               w += (size_t)(N + 4) * 4;
    int* hist = (int*)w;               w += (size_t)NBKT * NB_CH * 4;
    int* bstart = (int*)w;             w += (size_t)(NBKT + 4) * 4;
    int* rowsum = (int*)w;             w += (size_t)(NBKT + 4) * 4;
    int* rowbase = (int*)w;            w += (size_t)(NBKT + 4) * 4;
    __half* xh = (__half*)w;           w += (size_t)N * F * 2;
    __half* hA = (__half*)w;           w += (size_t)N * F * 2;
    __half* hB = (__half*)w;           w += (size_t)N * F * 2;

    const int nblk_nodes = N / 16;                   // 12500

    // ---- CSR build (bucket counting sort; hierarchical scan) + x fp16 convert ----
    x2h_kernel<<<(N * F / 2 + 255) / 256, 256, 0, stream>>>(x, xh);
    hist_kernel<<<NB_CH, 1024, 0, stream>>>(dst, hist);
    scanA_kernel<<<NBKT, 256, 0, stream>>>(hist, rowsum);
    scanB_kernel<<<1, 256, 0, stream>>>(rowsum, rowbase, bstart);
    scanC_kernel<<<NBKT, 256, 0, stream>>>(hist, rowbase);
    bucket_scatter_kernel<<<NB_CH, 1024, 0, stream>>>(src, dst, hist, pairs);
    build_csr_kernel<<<NBKT, 256, 0, stream>>>(pairs, bstart, off, col);

    // ---- 4 fused layers (ping-pong hA/hB) ----
    layer_kernel<<<nblk_nodes, 256, 0, stream>>>(xh, hA, off, col,
        c1_Wl, c1_bl, c1_Wr, nullptr, nullptr, 0, nullptr);
    layer_kernel<<<nblk_nodes, 256, 0, stream>>>(hA, hB, off, col,
        c1_Wl + F * F, c1_bl + F, c1_Wr + F * F, fc1_W, fc1_b, 1, nullptr);
    layer_kernel<<<nblk_nodes, 256, 0, stream>>>(hB, hA, off, col,
        c2_Wl, c2_bl, c2_Wr, nullptr, nullptr, 0, nullptr);
    layer_kernel<<<nblk_nodes, 256, 0, stream>>>(hA, nullptr, off, col,
        c2_Wl + F * F, c2_bl + F, c2_Wr + F * F, fc2_W, fc2_b, 2, out);
}